// Round 1
// 173.422 us; speedup vs baseline: 1.0101x; 1.0101x over previous
//
#include <hip/hip_runtime.h>

typedef __bf16 bf16;
typedef __bf16 bf16x8 __attribute__((ext_vector_type(8)));
typedef float f32x4 __attribute__((ext_vector_type(4)));

#define M_TOT 4096
#define D_IN  784
#define HALF  392
#define MID   1000
#define K0PAD 448   // 392 -> mult of 64
#define NPAD  1024  // 1000 padded

// ---------- async global->LDS 16B ----------
__device__ __forceinline__ void g2l16(const bf16* g, bf16* l) {
  __builtin_amdgcn_global_load_lds(
      (__attribute__((address_space(1))) void*)(g),
      (__attribute__((address_space(3))) void*)(l),
      16, 0, 0);
}

// ---------- 32x32 weight-transpose tile: W (KxN f32) -> WT (Npad x Kpad bf16) ----------
__device__ __forceinline__ void wtrans_tile(const float* __restrict__ W, bf16* __restrict__ WT,
                                            int K, int N, int Kpad, int tn, int tk,
                                            float (*tb)[33], int tid) {
  int n0 = tn * 32, k0 = tk * 32;
  int tx = tid & 31, ty = tid >> 5;
#pragma unroll
  for (int r = 0; r < 4; ++r) {
    int k = k0 + ty + 8 * r, n = n0 + tx;
    tb[ty + 8 * r][tx] = (k < K && n < N) ? W[(size_t)k * N + n] : 0.f;
  }
  __syncthreads();
#pragma unroll
  for (int r = 0; r < 4; ++r) {
    int n = n0 + ty + 8 * r, k = k0 + tx;
    WT[(size_t)n * Kpad + k] = (bf16)tb[tx][ty + 8 * r];
  }
}

// ---------- prep: vectorized pack x-even -> A0 (bf16), W_in transpose, ldj ----------
// grid: 896 pack blocks + 448 WT0 blocks = 1344
__global__ void prep_k(const float* __restrict__ x, const float* __restrict__ ldj,
                       const float* __restrict__ W_in,
                       bf16* __restrict__ A0, bf16* __restrict__ WT0,
                       float* __restrict__ y) {
  __shared__ float tb[32][33];
  const int b = blockIdx.x, tid = threadIdx.x;
  if (b < 896) {  // pack: each thread produces 8 consecutive k of one row
    int g = b * 256 + tid;          // 0 .. 229375
    int m = g / 56;                 // 56 groups of 8 cover K0PAD=448
    int kq = g - m * 56, k0 = kq * 8;
    bf16x8 v;
    if (k0 < HALF) {                // kq<=48 -> k0<=384, all 8 k valid (<392)
      const float4* xr = (const float4*)(x + (size_t)m * D_IN + 2 * k0);
      float4 a0 = xr[0], a1 = xr[1], a2 = xr[2], a3 = xr[3];
      v[0] = (bf16)a0.x; v[1] = (bf16)a0.z;
      v[2] = (bf16)a1.x; v[3] = (bf16)a1.z;
      v[4] = (bf16)a2.x; v[5] = (bf16)a2.z;
      v[6] = (bf16)a3.x; v[7] = (bf16)a3.z;
    } else {
#pragma unroll
      for (int j = 0; j < 8; ++j) v[j] = (bf16)0.f;
    }
    *(bf16x8*)(A0 + (size_t)m * K0PAD + k0) = v;
    if (b == 0 && tid == 0) y[(size_t)M_TOT * D_IN] = ldj[0];
    return;
  }
  // W_in: (392 x 1000) -> WT0 (1024 x 448)
  int u = b - 896;
  wtrans_tile(W_in, WT0, HALF, MID, K0PAD, u & 31, u >> 5, tb, tid);
}

// ---------- GEMM: BM x 64 tile, BK=64, 4 waves, XOR-swizzled LDS ----------
// Linear grid: id < nb -> gemm block (bm = id % (M/BM), bn = id / (M/BM));
// id >= nb -> carried weight-transpose block for the NEXT dispatch's B operand
// (visibility guaranteed by the stream's dispatch boundary).
// EPI=0: C = relu(A@BT^T + bias) bf16, stride NPAD.
// EPI=1: y pairs: y[m][2n]=x[m][2n]; y[m][2n+1]=x[m][2n+1]+acc+bias[n] (n<HALF)
template <int BM, int BN, int EPI, int K>
__global__ __launch_bounds__(256, (BM > 64 ? 2 : 4))
void gemm_k(const bf16* __restrict__ A, const bf16* __restrict__ BT,
            const float* __restrict__ bias, int bias_n,
            bf16* __restrict__ C,
            const float* __restrict__ x, float* __restrict__ y, int nb,
            const float* __restrict__ Wx, bf16* __restrict__ WTx,
            int wK, int wN, int wKpad, int wTN) {
  constexpr int BK = 64;
  constexpr int MT = BM / 32, NT = BN / 32;   // 16x16 frags per wave (m, n)
  constexpr int KT = K / BK;
  constexpr int NBM = M_TOT / BM;
  alignas(16) __shared__ bf16 ldsA[BM * BK];
  alignas(16) __shared__ bf16 ldsB[BN * BK];
  const int tid = threadIdx.x;
  const int id = blockIdx.x;

  if (id >= nb) {  // carried transpose
    int u = id - nb;
    wtrans_tile(Wx, WTx, wK, wN, wKpad, u % wTN, u / wTN, (float(*)[33])ldsA, tid);
    return;
  }

  const int wave = tid >> 6, lane = tid & 63;
  const int bm = id % NBM, bn = id / NBM;

  // staging: 8 lanes/row (64 cols * 2B = 128B); global 16B-group XOR-swizzled by row%8.
  const int srow = lane >> 3;
  const int sq = (lane & 7) ^ srow;
  const bf16* gA = A + ((size_t)bm * BM + wave * (BM / 4) + srow) * K + sq * 8;
  const bf16* gB = BT + ((size_t)bn * BN + wave * (BN / 4) + srow) * K + sq * 8;
  bf16* lA = &ldsA[wave * (BM / 4) * BK];
  bf16* lB = &ldsB[wave * (BN / 4) * BK];

  const int mlane = lane & 15, quad = lane >> 4;
  const int wm = (wave & 1) * (BM / 2), wn = (wave >> 1) * (BN / 2);
  const int axor = mlane & 7;
  const bf16* raBase = &ldsA[(wm + mlane) * BK];
  const bf16* rbBase = &ldsB[(wn + mlane) * BK];

  f32x4 acc[MT][NT] = {};

  // stage tile 0
#pragma unroll
  for (int i = 0; i < BM / 32; ++i) g2l16(gA + (size_t)(8 * i) * K, lA + (8 * i) * BK);
#pragma unroll
  for (int i = 0; i < BN / 32; ++i) g2l16(gB + (size_t)(8 * i) * K, lB + (8 * i) * BK);

  for (int kt = 0; kt < KT; ++kt) {
    __syncthreads();  // staging of tile kt complete
    bf16x8 af[2][MT], bfr[2][NT];
#pragma unroll
    for (int s = 0; s < 2; ++s) {
      const int co = ((s * 4 + quad) ^ axor) * 8;
#pragma unroll
      for (int i = 0; i < MT; ++i) af[s][i] = *(const bf16x8*)(raBase + i * 16 * BK + co);
#pragma unroll
      for (int i = 0; i < NT; ++i) bfr[s][i] = *(const bf16x8*)(rbBase + i * 16 * BK + co);
    }
    __syncthreads();  // all waves done reading LDS
    if (kt + 1 < KT) {
      const size_t off = (size_t)(kt + 1) * BK;
#pragma unroll
      for (int i = 0; i < BM / 32; ++i) g2l16(gA + off + (size_t)(8 * i) * K, lA + (8 * i) * BK);
#pragma unroll
      for (int i = 0; i < BN / 32; ++i) g2l16(gB + off + (size_t)(8 * i) * K, lB + (8 * i) * BK);
    }
#pragma unroll
    for (int s = 0; s < 2; ++s)
#pragma unroll
      for (int mt = 0; mt < MT; ++mt)
#pragma unroll
        for (int nt = 0; nt < NT; ++nt)
          acc[mt][nt] = __builtin_amdgcn_mfma_f32_16x16x32_bf16(
              af[s][mt], bfr[s][nt], acc[mt][nt], 0, 0, 0);
  }

  const int ng0 = bn * BN + wn + mlane;
  const int mg0 = bm * BM + wm + quad * 4;

  if (EPI == 0) {
    float bv[NT];
#pragma unroll
    for (int nt = 0; nt < NT; ++nt) {
      int n = ng0 + nt * 16;
      bv[nt] = (n < bias_n) ? bias[n] : 0.f;
    }
#pragma unroll
    for (int mt = 0; mt < MT; ++mt)
#pragma unroll
      for (int nt = 0; nt < NT; ++nt)
#pragma unroll
        for (int r = 0; r < 4; ++r) {
          int m = mg0 + mt * 16 + r;
          int n = ng0 + nt * 16;
          float v = fmaxf(acc[mt][nt][r] + bv[nt], 0.f);
          C[(size_t)m * NPAD + n] = (bf16)v;
        }
  } else {
    const float2* x2 = (const float2*)x;
    float2* y2 = (float2*)y;
#pragma unroll
    for (int nt = 0; nt < NT; ++nt) {
      int n = ng0 + nt * 16;
      if (n < HALF) {
        float bb = bias[n];
#pragma unroll
        for (int mt = 0; mt < MT; ++mt)
#pragma unroll
          for (int r = 0; r < 4; ++r) {
            int m = mg0 + mt * 16 + r;
            size_t off = (size_t)m * (D_IN / 2) + n;
            float2 v = x2[off];
            v.y += acc[mt][nt][r] + bb;
            y2[off] = v;
          }
      }
    }
  }
}

extern "C" void kernel_launch(void* const* d_in, const int* in_sizes, int n_in,
                              void* d_out, int out_size, void* d_ws, size_t ws_size,
                              hipStream_t stream) {
  const float* x     = (const float*)d_in[0];
  const float* ldj   = (const float*)d_in[1];
  const float* W_in  = (const float*)d_in[2];
  const float* b_in  = (const float*)d_in[3];
  const float* W_hid = (const float*)d_in[4];
  const float* b_hid = (const float*)d_in[5];
  const float* W_out = (const float*)d_in[6];
  const float* b_out = (const float*)d_in[7];
  float* y = (float*)d_out;

  // workspace layout (bytes, 256-aligned)
  char* p = (char*)d_ws;
  bf16* A0  = (bf16*)(p + 0);           // 4096 x 448   (3,670,016 B)
  bf16* H0  = (bf16*)(p + 3670016);     // 4096 x 1024  (8,388,608 B)
  bf16* H1  = (bf16*)(p + 12058624);    // 4096 x 1024
  bf16* WT0 = (bf16*)(p + 20447232);    // 1024 x 448   (917,504 B)
  bf16* WTh = (bf16*)(p + 21364736);    // 4 x 1024 x 1024 (8,388,608 B)
  bf16* WT5 = (bf16*)(p + 29753344);    // 512 x 1024   (1,048,576 B)

  const size_t WH = (size_t)NPAD * NPAD;
  const size_t WS = (size_t)MID * MID;

  // --- prep: pack (vectorized) + WT0 only; other transposes ride the GEMM dispatches ---
  prep_k<<<dim3(896 + 448), 256, 0, stream>>>(x, ldj, W_in, A0, WT0, y);

  // --- MLP: 6 GEMMs. Hidden layers: 128x64 tiles, 512 blocks (2/CU).
  //     Dispatch i carries the transpose whose result is needed by dispatch i+1. ---
  gemm_k<128, 64, 0, K0PAD><<<dim3(512 + 1024), 256, 0, stream>>>(
      A0, WT0, b_in, MID, H0, nullptr, nullptr, 512,
      W_hid + 0 * WS, WTh + 0 * WH, MID, MID, NPAD, 32);
  gemm_k<128, 64, 0, NPAD><<<dim3(512 + 1024), 256, 0, stream>>>(
      H0, WTh + 0 * WH, b_hid + 0 * MID, MID, H1, nullptr, nullptr, 512,
      W_hid + 1 * WS, WTh + 1 * WH, MID, MID, NPAD, 32);
  gemm_k<128, 64, 0, NPAD><<<dim3(512 + 1024), 256, 0, stream>>>(
      H1, WTh + 1 * WH, b_hid + 1 * MID, MID, H0, nullptr, nullptr, 512,
      W_hid + 2 * WS, WTh + 2 * WH, MID, MID, NPAD, 32);
  gemm_k<128, 64, 0, NPAD><<<dim3(512 + 1024), 256, 0, stream>>>(
      H0, WTh + 2 * WH, b_hid + 2 * MID, MID, H1, nullptr, nullptr, 512,
      W_hid + 3 * WS, WTh + 3 * WH, MID, MID, NPAD, 32);
  gemm_k<128, 64, 0, NPAD><<<dim3(512 + 512), 256, 0, stream>>>(
      H1, WTh + 3 * WH, b_hid + 3 * MID, MID, H0, nullptr, nullptr, 512,
      W_out, WT5, MID, HALF, NPAD, 16);
  // final: writes BOTH interleaved columns (even = copy of x, odd = second + shift)
  gemm_k<64, 64, 1, NPAD><<<dim3(512), 256, 0, stream>>>(
      H0, WT5, b_out, HALF, nullptr, x, y, 512,
      nullptr, nullptr, 0, 0, 0, 1);
}

// Round 3
// 169.369 us; speedup vs baseline: 1.0343x; 1.0239x over previous
//
#include <hip/hip_runtime.h>

typedef __bf16 bf16;
typedef __bf16 bf16x8 __attribute__((ext_vector_type(8)));
typedef float f32x4 __attribute__((ext_vector_type(4)));

#define M_TOT 4096
#define D_IN  784
#define HALF  392
#define MID   1000
#define K0PAD 448   // 392 -> mult of 64
#define NPAD  1024  // 1000 padded

// ---------- async global->LDS 16B ----------
__device__ __forceinline__ void g2l16(const bf16* g, bf16* l) {
  __builtin_amdgcn_global_load_lds(
      (__attribute__((address_space(1))) void*)(g),
      (__attribute__((address_space(3))) void*)(l),
      16, 0, 0);
}

// ---------- 32x32 weight-transpose tile: W (KxN f32) -> WT (Npad x Kpad bf16) ----------
__device__ __forceinline__ void wtrans_tile(const float* __restrict__ W, bf16* __restrict__ WT,
                                            int K, int N, int Kpad, int tn, int tk,
                                            float (*tb)[33], int tid) {
  int n0 = tn * 32, k0 = tk * 32;
  int tx = tid & 31, ty = tid >> 5;
#pragma unroll
  for (int r = 0; r < 4; ++r) {
    int k = k0 + ty + 8 * r, n = n0 + tx;
    tb[ty + 8 * r][tx] = (k < K && n < N) ? W[(size_t)k * N + n] : 0.f;
  }
  __syncthreads();
#pragma unroll
  for (int r = 0; r < 4; ++r) {
    int n = n0 + ty + 8 * r, k = k0 + tx;
    WT[(size_t)n * Kpad + k] = (bf16)tb[tx][ty + 8 * r];
  }
}

// ---------- prep: vectorized pack x-even -> A0 (bf16), W_in transpose, ldj ----------
// grid: 896 pack blocks + 448 WT0 blocks = 1344
__global__ void prep_k(const float* __restrict__ x, const float* __restrict__ ldj,
                       const float* __restrict__ W_in,
                       bf16* __restrict__ A0, bf16* __restrict__ WT0,
                       float* __restrict__ y) {
  __shared__ float tb[32][33];
  const int b = blockIdx.x, tid = threadIdx.x;
  if (b < 896) {  // pack: each thread produces 8 consecutive k of one row
    int g = b * 256 + tid;          // 0 .. 229375
    int m = g / 56;                 // 56 groups of 8 cover K0PAD=448
    int kq = g - m * 56, k0 = kq * 8;
    bf16x8 v;
    if (k0 < HALF) {                // kq<=48 -> k0<=384, all 8 k valid (<392)
      const float4* xr = (const float4*)(x + (size_t)m * D_IN + 2 * k0);
      float4 a0 = xr[0], a1 = xr[1], a2 = xr[2], a3 = xr[3];
      v[0] = (bf16)a0.x; v[1] = (bf16)a0.z;
      v[2] = (bf16)a1.x; v[3] = (bf16)a1.z;
      v[4] = (bf16)a2.x; v[5] = (bf16)a2.z;
      v[6] = (bf16)a3.x; v[7] = (bf16)a3.z;
    } else {
#pragma unroll
      for (int j = 0; j < 8; ++j) v[j] = (bf16)0.f;
    }
    *(bf16x8*)(A0 + (size_t)m * K0PAD + k0) = v;
    if (b == 0 && tid == 0) y[(size_t)M_TOT * D_IN] = ldj[0];
    return;
  }
  // W_in: (392 x 1000) -> WT0 (1024 x 448)
  int u = b - 896;
  wtrans_tile(W_in, WT0, HALF, MID, K0PAD, u & 31, u >> 5, tb, tid);
}

// ---------- GEMM: BM x BN tile, BK = BKT, 4 waves, XOR-swizzled LDS ----------
// Linear grid: id < nb -> gemm block (bm = id % (M/BM), bn = id / (M/BM));
// id >= nb -> carried weight-transpose block for the NEXT dispatch's B operand.
// Swizzle: LDS[row][chunk] holds global chunk (chunk ^ (row&7)); staged via
// pre-swizzled global source (linear LDS dest), read with matching XOR.
// EPI=0: C = relu(A@BT^T + bias) bf16, stride NPAD.
// EPI=1: y pairs: y[m][2n]=x[m][2n]; y[m][2n+1]=x[m][2n+1]+acc+bias[n] (n<HALF)
template <int BM, int BN, int EPI, int K, int BKT>
__global__ __launch_bounds__(256, ((BM * BKT > 64 * 64) ? 2 : 4))
void gemm_k(const bf16* __restrict__ A, const bf16* __restrict__ BT,
            const float* __restrict__ bias, int bias_n,
            bf16* __restrict__ C,
            const float* __restrict__ x, float* __restrict__ y, int nb,
            const float* __restrict__ Wx, bf16* __restrict__ WTx,
            int wK, int wN, int wKpad, int wTN) {
  constexpr int BK = BKT;
  constexpr int MT = BM / 32, NT = BN / 32;   // 16x16 frags per wave (m, n)
  constexpr int SL = BK / 32;                 // k-slices per K-step
  constexpr int KT = K / BK;
  constexpr int NBM = M_TOT / BM;
  constexpr int LPR = BK / 8;                 // lanes per staged row
  constexpr int RPI = 512 / BK;               // rows per g2l16 instr (wave)
  constexpr int AI = (BM / 4) / RPI;          // A stage instrs per wave
  constexpr int BI = (BN / 4) / RPI;          // B stage instrs per wave
  static_assert(K % BK == 0, "K must be divisible by BK");
  alignas(16) __shared__ bf16 ldsA[BM * BK];
  alignas(16) __shared__ bf16 ldsB[BN * BK];
  const int tid = threadIdx.x;
  const int id = blockIdx.x;

  if (id >= nb) {  // carried transpose for next dispatch
    int u = id - nb;
    wtrans_tile(Wx, WTx, wK, wN, wKpad, u % wTN, u / wTN, (float(*)[33])ldsA, tid);
    return;
  }

  const int wave = tid >> 6, lane = tid & 63;
  const int bm = id % NBM, bn = id / NBM;

  const int srow = lane / LPR;
  const int scol = lane % LPR;
  const bf16* gAb = A + ((size_t)bm * BM + wave * (BM / 4)) * K;
  const bf16* gBb = BT + ((size_t)bn * BN + wave * (BN / 4)) * K;
  bf16* lA = &ldsA[wave * (BM / 4) * BK];
  bf16* lB = &ldsB[wave * (BN / 4) * BK];

  const int mlane = lane & 15, quad = lane >> 4;
  const int wm = (wave & 1) * (BM / 2), wn = (wave >> 1) * (BN / 2);
  const int axor = mlane & 7;
  const bf16* raBase = &ldsA[(wm + mlane) * BK];
  const bf16* rbBase = &ldsB[(wn + mlane) * BK];

  f32x4 acc[MT][NT] = {};

  auto stage = [&](int koff) {
#pragma unroll
    for (int i = 0; i < AI; ++i) {
      int r = i * RPI + srow;
      g2l16(gAb + (size_t)r * K + koff + (scol ^ (r & 7)) * 8, lA + i * RPI * BK);
    }
#pragma unroll
    for (int i = 0; i < BI; ++i) {
      int r = i * RPI + srow;
      g2l16(gBb + (size_t)r * K + koff + (scol ^ (r & 7)) * 8, lB + i * RPI * BK);
    }
  };

  stage(0);

  for (int kt = 0; kt < KT; ++kt) {
    __syncthreads();  // staging of tile kt complete
    bf16x8 af[SL][MT], bfr[SL][NT];
#pragma unroll
    for (int s = 0; s < SL; ++s) {
      const int co = ((s * 4 + quad) ^ axor) * 8;
#pragma unroll
      for (int i = 0; i < MT; ++i) af[s][i] = *(const bf16x8*)(raBase + i * 16 * BK + co);
#pragma unroll
      for (int i = 0; i < NT; ++i) bfr[s][i] = *(const bf16x8*)(rbBase + i * 16 * BK + co);
    }
    __syncthreads();  // all waves done reading LDS
    if (kt + 1 < KT) stage((kt + 1) * BK);
#pragma unroll
    for (int s = 0; s < SL; ++s)
#pragma unroll
      for (int mt = 0; mt < MT; ++mt)
#pragma unroll
        for (int nt = 0; nt < NT; ++nt)
          acc[mt][nt] = __builtin_amdgcn_mfma_f32_16x16x32_bf16(
              af[s][mt], bfr[s][nt], acc[mt][nt], 0, 0, 0);
  }

  const int ng0 = bn * BN + wn + mlane;
  const int mg0 = bm * BM + wm + quad * 4;

  if (EPI == 0) {
    float bv[NT];
#pragma unroll
    for (int nt = 0; nt < NT; ++nt) {
      int n = ng0 + nt * 16;
      bv[nt] = (n < bias_n) ? bias[n] : 0.f;
    }
#pragma unroll
    for (int mt = 0; mt < MT; ++mt)
#pragma unroll
      for (int nt = 0; nt < NT; ++nt)
#pragma unroll
        for (int r = 0; r < 4; ++r) {
          int m = mg0 + mt * 16 + r;
          int n = ng0 + nt * 16;
          float v = fmaxf(acc[mt][nt][r] + bv[nt], 0.f);
          C[(size_t)m * NPAD + n] = (bf16)v;
        }
  } else {
    const float2* x2 = (const float2*)x;
    float2* y2 = (float2*)y;
#pragma unroll
    for (int nt = 0; nt < NT; ++nt) {
      int n = ng0 + nt * 16;
      if (n < HALF) {
        float bb = bias[n];
#pragma unroll
        for (int mt = 0; mt < MT; ++mt)
#pragma unroll
          for (int r = 0; r < 4; ++r) {
            int m = mg0 + mt * 16 + r;
            size_t off = (size_t)m * (D_IN / 2) + n;
            float2 v = x2[off];
            v.y += acc[mt][nt][r] + bb;
            y2[off] = v;
          }
      }
    }
  }
}

extern "C" void kernel_launch(void* const* d_in, const int* in_sizes, int n_in,
                              void* d_out, int out_size, void* d_ws, size_t ws_size,
                              hipStream_t stream) {
  const float* x     = (const float*)d_in[0];
  const float* ldj   = (const float*)d_in[1];
  const float* W_in  = (const float*)d_in[2];
  const float* b_in  = (const float*)d_in[3];
  const float* W_hid = (const float*)d_in[4];
  const float* b_hid = (const float*)d_in[5];
  const float* W_out = (const float*)d_in[6];
  const float* b_out = (const float*)d_in[7];
  float* y = (float*)d_out;

  // workspace layout (bytes, 256-aligned)
  char* p = (char*)d_ws;
  bf16* A0  = (bf16*)(p + 0);           // 4096 x 448   (3,670,016 B)
  bf16* H0  = (bf16*)(p + 3670016);     // 4096 x 1024  (8,388,608 B)
  bf16* H1  = (bf16*)(p + 12058624);    // 4096 x 1024
  bf16* WT0 = (bf16*)(p + 20447232);    // 1024 x 448   (917,504 B)
  bf16* WTh = (bf16*)(p + 21364736);    // 4 x 1024 x 1024 (8,388,608 B)
  bf16* WT5 = (bf16*)(p + 29753344);    // 512 x 1024   (1,048,576 B)

  const size_t WH = (size_t)NPAD * NPAD;
  const size_t WS = (size_t)MID * MID;

  // --- prep: pack (vectorized) + WT0 only; other transposes ride the GEMM dispatches ---
  prep_k<<<dim3(896 + 448), 256, 0, stream>>>(x, ldj, W_in, A0, WT0, y);

  // --- MLP: 6 GEMMs. Hidden layers: 128x64 tiles, BK=128 (KT=8), 512 blocks (2/CU).
  //     Dispatch i carries the transpose whose result is needed by dispatch i+1. ---
  gemm_k<128, 64, 0, K0PAD, 64><<<dim3(512 + 1024), 256, 0, stream>>>(
      A0, WT0, b_in, MID, H0, nullptr, nullptr, 512,
      W_hid + 0 * WS, WTh + 0 * WH, MID, MID, NPAD, 32);
  gemm_k<128, 64, 0, NPAD, 128><<<dim3(512 + 1024), 256, 0, stream>>>(
      H0, WTh + 0 * WH, b_hid + 0 * MID, MID, H1, nullptr, nullptr, 512,
      W_hid + 1 * WS, WTh + 1 * WH, MID, MID, NPAD, 32);
  gemm_k<128, 64, 0, NPAD, 128><<<dim3(512 + 1024), 256, 0, stream>>>(
      H1, WTh + 1 * WH, b_hid + 1 * MID, MID, H0, nullptr, nullptr, 512,
      W_hid + 2 * WS, WTh + 2 * WH, MID, MID, NPAD, 32);
  gemm_k<128, 64, 0, NPAD, 128><<<dim3(512 + 1024), 256, 0, stream>>>(
      H0, WTh + 2 * WH, b_hid + 2 * MID, MID, H1, nullptr, nullptr, 512,
      W_hid + 3 * WS, WTh + 3 * WH, MID, MID, NPAD, 32);
  gemm_k<128, 64, 0, NPAD, 128><<<dim3(512 + 512), 256, 0, stream>>>(
      H1, WTh + 3 * WH, b_hid + 3 * MID, MID, H0, nullptr, nullptr, 512,
      W_out, WT5, MID, HALF, NPAD, 16);
  // final: writes BOTH interleaved columns (even = copy of x, odd = second + shift)
  gemm_k<64, 64, 1, NPAD, 64><<<dim3(512), 256, 0, stream>>>(
      H0, WT5, b_out, HALF, nullptr, x, y, 512,
      nullptr, nullptr, 0, 0, 0, 1);
}